// Round 6
// baseline (246.954 us; speedup 1.0000x reference)
//
#include <hip/hip_runtime.h>
#include <hip/hip_bf16.h>
#include <math.h>

// B=4, N=4096, F=512, C=64. M = B*N = 16384 rows.
#define M_ROWS 16384
#define F_DIM 512
#define C_DIM 64

typedef short bf16x8 __attribute__((ext_vector_type(8)));
typedef float floatx4 __attribute__((ext_vector_type(4)));
typedef unsigned short ushortx8 __attribute__((ext_vector_type(8)));
typedef unsigned short ushortx4 __attribute__((ext_vector_type(4)));

static __device__ __forceinline__ unsigned short f2bf(float x) {
    __hip_bfloat16 h = __float2bfloat16(x);   // RN
    return *reinterpret_cast<unsigned short*>(&h);
}
static __device__ __forceinline__ float bf2f(unsigned short h) {
    unsigned int u = ((unsigned int)h) << 16;
    return __builtin_bit_cast(float, u);
}

// LDS-only barrier: global loads stay in flight (no vmcnt(0) drain).
static __device__ __forceinline__ void lgkm_barrier() {
    asm volatile("s_waitcnt lgkmcnt(0)\n\ts_barrier" ::: "memory");
}

// ---------------------------------------------------------------------------
// Frag-linear layouts (MFMA operand order): element (n,k) of a 16-col group
// lives at lane=(k>>3&3)*16+(n&15), j=k&7 -> [group][lane][8] contiguous.
// Same mapping serves A-operand (n = row) and B-operand (n = col).
//   wt   : group = (c>>4)*16 + (k>>5)                  (640 cols x 512 k)
//   v_hi : group = (row>>4)*16 + (k>>5)                (16384 rows x 512 k)
//   h_sw : [b][mtile(64)][group=(Fcol>>4)*2+(mloc>>5)][lane][8]
// ---------------------------------------------------------------------------

// Kernel 0a: weight transpose + bf16 hi/lo split -> frag-linear.
__global__ __launch_bounds__(64) void prep_w_kernel(
    const float* __restrict__ Wf, const float* __restrict__ Wg,
    const float* __restrict__ Wh,
    unsigned short* __restrict__ wt_hi, unsigned short* __restrict__ wt_lo)
{
    const int c = blockIdx.x;
    const int t = threadIdx.x;
    const float* W; int ld, cl;
    if (c < 64)       { W = Wf; ld = C_DIM; cl = c; }
    else if (c < 128) { W = Wg; ld = C_DIM; cl = c - 64; }
    else              { W = Wh; ld = F_DIM; cl = c - 128; }
    const int ng = c >> 4, l16 = c & 15;
    for (int k = t; k < F_DIM; k += 64) {
        const float x = W[(size_t)k * ld + cl];
        const unsigned short h = f2bf(x);
        const int kh = k >> 5, qd = (k >> 3) & 3, j = k & 7;
        const size_t off = (((size_t)(ng * 16 + kh) * 64) + qd * 16 + l16) * 8 + j;
        wt_hi[off] = h;
        wt_lo[off] = f2bf(x - bf2f(h));
    }
}

// ---------------------------------------------------------------------------
// Kernel 0b: V fp32 -> bf16 hi/lo, A-frag-linear. One octet (8 k's of one
// row) per thread; writes are 16 B/lane fully coalesced. Removes the per-
// K-step VALU hi/lo split + LDS round-trip from embed's hot loop (which was
// ~95 us of runtime for a 7 us MFMA-floor kernel).
// ---------------------------------------------------------------------------
__global__ __launch_bounds__(256) void conv_v_kernel(
    const float* __restrict__ V,
    unsigned short* __restrict__ v_hi, unsigned short* __restrict__ v_lo)
{
    const int o   = blockIdx.x * 256 + threadIdx.x;   // octet index
    const int l16 = o & 15, kq = (o >> 4) & 3, kg = (o >> 6) & 15, rg = o >> 10;
    const int row = rg * 16 + l16;
    const int k   = kg * 32 + kq * 8;
    const float4 x0 = *(const float4*)(V + (size_t)row * F_DIM + k);
    const float4 x1 = *(const float4*)(V + (size_t)row * F_DIM + k + 4);
    const float xs[8] = {x0.x, x0.y, x0.z, x0.w, x1.x, x1.y, x1.z, x1.w};
    ushortx8 hi, lo;
    #pragma unroll
    for (int j = 0; j < 8; ++j) {
        const unsigned short h = f2bf(xs[j]);
        hi[j] = h;
        lo[j] = f2bf(xs[j] - bf2f(h));
    }
    *(ushortx8*)(v_hi + (size_t)o * 8) = hi;
    *(ushortx8*)(v_lo + (size_t)o * 8) = lo;
}

// ---------------------------------------------------------------------------
// Kernel 1: embed GEMM v2 — NO LDS, NO BARRIERS. A-frags load directly from
// frag-linear v_hi/v_lo (global, L2-resident: with grid (256,5), XCD =
// bid%8 sees the same 2.1 MB v_hi row-chunk in all 5 col-passes). Inner
// loop is pure {6 global b128 loads + 8 MFMA} (fg: 12 + 24); 20 waves/CU
// of TLP hide latency. blockIdx.y: 0 -> f|g fused (hi/lo 3-MFMA path),
// 1..4 -> h cols (y-1)*128. Wave w owns cols w*32..+32.
// ---------------------------------------------------------------------------
#define BM 64

__global__ __launch_bounds__(256, 4) void embed_mfma_kernel(
    const unsigned short* __restrict__ v_hi, const unsigned short* __restrict__ v_lo,
    const unsigned short* __restrict__ wt_hi, const unsigned short* __restrict__ wt_lo,
    const float* __restrict__ bf, const float* __restrict__ bg,
    const float* __restrict__ bh,
    unsigned short* __restrict__ f_bf, unsigned short* __restrict__ g_bf,
    unsigned short* __restrict__ h_sw)
{
    const int t  = threadIdx.x;
    const int q  = blockIdx.x;            // row-tile 0..255
    const int yb = blockIdx.y;            // col-pass 0..4
    const int R0 = q * BM;
    const bool fg = (yb == 0);
    const int cbase = fg ? 0 : yb * 128;  // wt col base (g at 64, h at 128+)

    const int w = t >> 6, lane = t & 63, quad = lane >> 4, l16 = lane & 15;
    const int ng0 = (cbase >> 4) + w * 2;
    const int rg0 = q * 4;

    floatx4 acc[4][2];
    #pragma unroll
    for (int rt = 0; rt < 4; ++rt)
        #pragma unroll
        for (int c = 0; c < 2; ++c)
            acc[rt][c] = (floatx4){0.f, 0.f, 0.f, 0.f};

    #pragma unroll 2
    for (int kg = 0; kg < 16; ++kg) {
        const bf16x8 b0 = *(const bf16x8*)(wt_hi + (((size_t)(ng0 * 16 + kg)) * 64 + lane) * 8);
        const bf16x8 b1 = *(const bf16x8*)(wt_hi + (((size_t)((ng0 + 1) * 16 + kg)) * 64 + lane) * 8);
        bf16x8 a[4];
        #pragma unroll
        for (int rt = 0; rt < 4; ++rt)
            a[rt] = *(const bf16x8*)(v_hi + (((size_t)(rg0 + rt) * 16 + kg) * 64 + lane) * 8);
        #pragma unroll
        for (int rt = 0; rt < 4; ++rt) {
            acc[rt][0] = __builtin_amdgcn_mfma_f32_16x16x32_bf16(a[rt], b0, acc[rt][0], 0, 0, 0);
            acc[rt][1] = __builtin_amdgcn_mfma_f32_16x16x32_bf16(a[rt], b1, acc[rt][1], 0, 0, 0);
        }
        if (fg) {
            const bf16x8 c0 = *(const bf16x8*)(wt_lo + (((size_t)(ng0 * 16 + kg)) * 64 + lane) * 8);
            const bf16x8 c1 = *(const bf16x8*)(wt_lo + (((size_t)((ng0 + 1) * 16 + kg)) * 64 + lane) * 8);
            bf16x8 al[4];
            #pragma unroll
            for (int rt = 0; rt < 4; ++rt)
                al[rt] = *(const bf16x8*)(v_lo + (((size_t)(rg0 + rt) * 16 + kg) * 64 + lane) * 8);
            #pragma unroll
            for (int rt = 0; rt < 4; ++rt) {
                acc[rt][0] = __builtin_amdgcn_mfma_f32_16x16x32_bf16(a[rt],  c0, acc[rt][0], 0, 0, 0);
                acc[rt][0] = __builtin_amdgcn_mfma_f32_16x16x32_bf16(al[rt], b0, acc[rt][0], 0, 0, 0);
                acc[rt][1] = __builtin_amdgcn_mfma_f32_16x16x32_bf16(a[rt],  c1, acc[rt][1], 0, 0, 0);
                acc[rt][1] = __builtin_amdgcn_mfma_f32_16x16x32_bf16(al[rt], b1, acc[rt][1], 0, 0, 0);
            }
        }
    }

    // ---- epilogue: bias + relu + bf16, route by wt column ----
    #pragma unroll
    for (int rt = 0; rt < 4; ++rt) {
        #pragma unroll
        for (int c = 0; c < 2; ++c) {
            const int wtc  = cbase + w * 32 + c * 16 + l16;   // 0..639
            const int rowl = rt * 16 + quad * 4;
            const float bias = fg ? (wtc < 64 ? bf[wtc] : bg[wtc - 64]) : bh[wtc - 128];
            const floatx4 v = acc[rt][c];
            if (fg) {
                unsigned short* dst = (wtc < 64) ? (f_bf + wtc) : (g_bf + wtc - 64);
                #pragma unroll
                for (int r = 0; r < 4; ++r) {
                    const float z = v[r] + bias;
                    dst[(size_t)(R0 + rowl + r) * C_DIM] = f2bf(z > 0.f ? z : 0.f);
                }
            } else {
                const int hc   = wtc - 128;                   // global F col
                const int grow = R0 + rowl;
                const int b    = grow >> 12, rl = grow & 4095;
                const int T    = rl >> 6, mloc = rl & 63;
                const int kh2  = mloc >> 5, q2 = (mloc >> 3) & 3, j0 = mloc & 7;
                ushortx4 st;
                #pragma unroll
                for (int r = 0; r < 4; ++r) {
                    const float z = v[r] + bias;
                    st[r] = f2bf(z > 0.f ? z : 0.f);
                }
                const size_t off = ((((size_t)(b * 64 + T) * 64) + (hc >> 4) * 2 + kh2) * 64
                                    + q2 * 16 + (hc & 15)) * 8 + j0;
                *(ushortx4*)(h_sw + off) = st;
            }
        }
    }
}

// ---------------------------------------------------------------------------
// Kernel 2: MFMA attention, fully fused, column-split, KT=128 PER BARRIER
// PAIR. Round-5 post-mortem: t_iter fits a + b*work with a ~670 cyc of
// fixed phase overhead per barrier pair (2-phase lockstep drain); R0 was
// fastest because it packed 36 MFMA/wave per pair. So: 2 key-mtiles (128
// keys) per iteration -> 32 iters, 40 MFMA/wave/iter, half the barriers.
// Partition otherwise IDENTICAL to round 4 (best fused, 108 us):
// QT=128, 16 waves, grid = 4b x 32qt x 2 col-halves = 256 blocks.
// Scores: wave w -> rows (w&7)*16, keys (w>>3)*32 of EACH 64-key subtile.
// PV: wave w -> all 128 rows x 16 F-cols (ch*256 + w*16); 4 k-slots.
// LDS: p[2][128][128] 64 KB + g[2][128][64] 32 KB, exact-stride + T2
// XOR-swizzle (byte ^= (row&7)<<4), verified 0-conflict. Barriers
// lgkm-only. XCD map: XCD = b*2+ch -> 2 MB h-half L2-resident.
// ---------------------------------------------------------------------------
#define QT 128

__global__ __launch_bounds__(1024, 4) void attn_mfma_kernel(
    const unsigned short* __restrict__ f_bf, const unsigned short* __restrict__ g_bf,
    const unsigned short* __restrict__ h_sw, const float* __restrict__ gamma,
    const float* __restrict__ V, float* __restrict__ out)
{
    __shared__ __align__(16) unsigned short p_lds[2][QT * 128];   // 64 KB
    __shared__ __align__(16) unsigned short g_lds[2][128 * 64];   // 32 KB
    __shared__ float l_red[2][QT];
    __shared__ float l_inv[QT];

    const int t = threadIdx.x;
    const int w = t >> 6, lane = t & 63, quad = lane >> 4, l16 = lane & 15;
    const int sr = (w & 7) * 16, sc = (w >> 3) * 32;   // score stripe

    const int bid = blockIdx.x;
    const int b   = (bid & 7) >> 1;
    const int ch  = bid & 1;
    const int qb  = bid >> 3;
    const int R0  = qb * QT;

    const unsigned short* fb    = f_bf + ((size_t)b * 4096 + R0) * C_DIM;
    const unsigned short* gb    = g_bf + (size_t)b * 4096 * C_DIM;
    const unsigned short* hbase = h_sw + (size_t)b * 64 * 32768;
    const int hgrp = (ch * 16 + w) * 2;   // wave's h group base (cols ch*256+w*16)

    bf16x8 f0, f1;
    {
        const unsigned short* fr = fb + (size_t)(sr + l16) * C_DIM + quad * 8;
        f0 = *(const bf16x8*)fr;
        f1 = *(const bf16x8*)(fr + 32);
    }
    const float gam = gamma[ch * 256 + w * 16 + l16];

    floatx4 acc[8];   // [row-tile]; wave's 16 cols
    #pragma unroll
    for (int rt = 0; rt < 8; ++rt)
        acc[rt] = (floatx4){0.f, 0.f, 0.f, 0.f};
    float run_l[4] = {0.f, 0.f, 0.f, 0.f};

    // cooperative g stage: thread t -> (row=t>>3 of 128, 16 B chunk), swizzled
    const int grow    = t >> 3, gc8 = (t & 7) * 8;           // shorts
    const int g_swoff = grow * 128 + ((gc8 * 2) ^ ((grow & 7) << 4));
    ushortx8 greg = *(const ushortx8*)(gb + (size_t)grow * C_DIM + gc8);

    for (int it = 0; it < 32; ++it) {
        const int buf = it & 1;

        // ---- h prefetch: wave's 4 KB (2 groups from each of 2 mtiles) ----
        const unsigned short* ht0 = hbase + (size_t)(2 * it) * 32768 + (size_t)hgrp * 512;
        const unsigned short* ht1 = ht0 + 32768;
        const bf16x8 h0 = *(const bf16x8*)(ht0 + (size_t)lane * 8);
        const bf16x8 h1 = *(const bf16x8*)(ht0 + 512 + (size_t)lane * 8);
        const bf16x8 h2 = *(const bf16x8*)(ht1 + (size_t)lane * 8);
        const bf16x8 h3 = *(const bf16x8*)(ht1 + 512 + (size_t)lane * 8);

        *(ushortx8*)((unsigned char*)&g_lds[buf][0] + g_swoff) = greg;
        if (it < 31)
            greg = *(const ushortx8*)(gb + (size_t)((it + 1) * 128 + grow) * C_DIM + gc8);
        lgkm_barrier();   // g[buf] visible

        const unsigned char* gB = (const unsigned char*)&g_lds[buf][0];
        unsigned char*       pB = (unsigned char*)&p_lds[buf][0];

        // ---- scores: rows sr..+16 x keys {s*64 + sc..+32}, s=0,1 ----
        #pragma unroll
        for (int sct = 0; sct < 4; ++sct) {
            const int s = sct >> 1, ct = sct & 1;
            const int srow = s * 64 + sc + ct * 16 + l16;    // g key-row
            const int sgw  = (srow & 7) << 4;
            const bf16x8 g0 = *(const bf16x8*)(gB + srow * 128 + ((quad * 16)      ^ sgw));
            const bf16x8 g1 = *(const bf16x8*)(gB + srow * 128 + ((quad * 16 + 64) ^ sgw));
            floatx4 cc = (floatx4){0.f, 0.f, 0.f, 0.f};
            cc = __builtin_amdgcn_mfma_f32_16x16x32_bf16(f0, g0, cc, 0, 0, 0);
            cc = __builtin_amdgcn_mfma_f32_16x16x32_bf16(f1, g1, cc, 0, 0, 0);
            #pragma unroll
            for (int r = 0; r < 4; ++r) {
                const float p = __expf(cc[r] - 32.f);
                run_l[r] += p;
                const int prow = sr + quad * 4 + r;
                const int bcol = (s * 64 + sc + ct * 16 + l16) * 2;
                *(unsigned short*)(pB + prow * 256 + (bcol ^ ((prow & 7) << 4))) = f2bf(p);
            }
        }
        lgkm_barrier();   // p[buf] visible

        // ---- PV: all 128 rows x wave's 16 cols, 4 k-slots ----
        #pragma unroll
        for (int rt = 0; rt < 8; ++rt) {
            const int prow = rt * 16 + l16;
            const int sw   = (prow & 7) << 4;
            const unsigned char* pr = pB + prow * 256;
            const bf16x8 pf0 = *(const bf16x8*)(pr + ((quad * 16)       ^ sw));
            const bf16x8 pf1 = *(const bf16x8*)(pr + ((quad * 16 + 64)  ^ sw));
            const bf16x8 pf2 = *(const bf16x8*)(pr + ((quad * 16 + 128) ^ sw));
            const bf16x8 pf3 = *(const bf16x8*)(pr + ((quad * 16 + 192) ^ sw));
            acc[rt] = __builtin_amdgcn_mfma_f32_16x16x32_bf16(pf0, h0, acc[rt], 0, 0, 0);
            acc[rt] = __builtin_amdgcn_mfma_f32_16x16x32_bf16(pf1, h1, acc[rt], 0, 0, 0);
            acc[rt] = __builtin_amdgcn_mfma_f32_16x16x32_bf16(pf2, h2, acc[rt], 0, 0, 0);
            acc[rt] = __builtin_amdgcn_mfma_f32_16x16x32_bf16(pf3, h3, acc[rt], 0, 0, 0);
        }
    }

    // ---- full row-sum l: shfl over l16, then LDS-sum across the 2 sc ----
    #pragma unroll
    for (int r = 0; r < 4; ++r) {
        float v = run_l[r];
        v += __shfl_xor(v, 1, 64);
        v += __shfl_xor(v, 2, 64);
        v += __shfl_xor(v, 4, 64);
        v += __shfl_xor(v, 8, 64);
        if (l16 == 0) l_red[w >> 3][sr + quad * 4 + r] = v;
    }
    __syncthreads();
    if (t < QT)
        l_inv[t] = 1.f / (l_red[0][t] + l_red[1][t]);
    __syncthreads();

    // ---- fused epilogue: out = gamma * O/l + V (fp32, final) ----
    const float* Vb = V   + ((size_t)b * 4096 + R0) * F_DIM;
    float*       ob = out + ((size_t)b * 4096 + R0) * F_DIM;
    const int col = ch * 256 + w * 16 + l16;
    #pragma unroll
    for (int rt = 0; rt < 8; ++rt) {
        #pragma unroll
        for (int r = 0; r < 4; ++r) {
            const int row = rt * 16 + quad * 4 + r;
            ob[(size_t)row * F_DIM + col] =
                gam * acc[rt][r] * l_inv[row] + Vb[(size_t)row * F_DIM + col];
        }
    }
}

// ---------------------------------------------------------------------------
extern "C" void kernel_launch(void* const* d_in, const int* in_sizes, int n_in,
                              void* d_out, int out_size, void* d_ws, size_t ws_size,
                              hipStream_t stream) {
    const float* V     = (const float*)d_in[0];
    const float* Wf    = (const float*)d_in[1];
    const float* bf    = (const float*)d_in[2];
    const float* Wg    = (const float*)d_in[3];
    const float* bg    = (const float*)d_in[4];
    const float* Wh    = (const float*)d_in[5];
    const float* bh    = (const float*)d_in[6];
    const float* gamma = (const float*)d_in[7];
    float* out = (float*)d_out;

    // ws: f 2MB | g 2MB | h_sw 16MB | wt_hi 0.64 | wt_lo 0.64 | v_hi 16MB | v_lo 16MB
    unsigned short* f_bf  = (unsigned short*)d_ws;
    unsigned short* g_bf  = f_bf + (size_t)M_ROWS * C_DIM;
    unsigned short* h_sw  = g_bf + (size_t)M_ROWS * C_DIM;
    unsigned short* wt_hi = h_sw + (size_t)4 * F_DIM * 4096;
    unsigned short* wt_lo = wt_hi + (size_t)640 * F_DIM;
    unsigned short* v_hi  = wt_lo + (size_t)640 * F_DIM;
    unsigned short* v_lo  = v_hi + (size_t)M_ROWS * F_DIM;

    conv_v_kernel<<<M_ROWS * F_DIM / 8 / 256, 256, 0, stream>>>(V, v_hi, v_lo);
    prep_w_kernel<<<640, 64, 0, stream>>>(Wf, Wg, Wh, wt_hi, wt_lo);
    embed_mfma_kernel<<<dim3(256, 5), 256, 0, stream>>>(
        v_hi, v_lo, wt_hi, wt_lo, bf, bg, bh, f_bf, g_bf, h_sw);
    attn_mfma_kernel<<<256, 1024, 0, stream>>>(f_bf, g_bf, h_sw, gamma, V, out);
}

// Round 7
// 218.142 us; speedup vs baseline: 1.1321x; 1.1321x over previous
//
#include <hip/hip_runtime.h>
#include <hip/hip_bf16.h>
#include <math.h>

// B=4, N=4096, F=512, C=64. M = B*N = 16384 rows.
#define M_ROWS 16384
#define F_DIM 512
#define C_DIM 64

typedef short bf16x8 __attribute__((ext_vector_type(8)));
typedef float floatx4 __attribute__((ext_vector_type(4)));
typedef unsigned short ushortx8 __attribute__((ext_vector_type(8)));
typedef unsigned short ushortx4 __attribute__((ext_vector_type(4)));

static __device__ __forceinline__ unsigned short f2bf(float x) {
    __hip_bfloat16 h = __float2bfloat16(x);   // RN
    return *reinterpret_cast<unsigned short*>(&h);
}
static __device__ __forceinline__ float bf2f(unsigned short h) {
    unsigned int u = ((unsigned int)h) << 16;
    return __builtin_bit_cast(float, u);
}

// LDS-only barrier: global loads stay in flight (no vmcnt(0) drain).
static __device__ __forceinline__ void lgkm_barrier() {
    asm volatile("s_waitcnt lgkmcnt(0)\n\ts_barrier" ::: "memory");
}

// ---------------------------------------------------------------------------
// Frag-linear layouts (MFMA operand order): element (n,k) of a 16-col group
// lives at lane=(k>>3&3)*16+(n&15), j=k&7 -> [group][lane][8] contiguous.
//   wt   : group = (c>>4)*16 + (k>>5)                  (640 cols x 512 k)
//   v_hi : group = (row>>4)*16 + (k>>5)                (16384 rows x 512 k)
//   h_sw : [b][mtile(64)][group=(Fcol>>4)*2+(mloc>>5)][lane][8]
// ---------------------------------------------------------------------------

// Kernel 0a: weight transpose + bf16 hi/lo split -> frag-linear.
__global__ __launch_bounds__(64) void prep_w_kernel(
    const float* __restrict__ Wf, const float* __restrict__ Wg,
    const float* __restrict__ Wh,
    unsigned short* __restrict__ wt_hi, unsigned short* __restrict__ wt_lo)
{
    const int c = blockIdx.x;
    const int t = threadIdx.x;
    const float* W; int ld, cl;
    if (c < 64)       { W = Wf; ld = C_DIM; cl = c; }
    else if (c < 128) { W = Wg; ld = C_DIM; cl = c - 64; }
    else              { W = Wh; ld = F_DIM; cl = c - 128; }
    const int ng = c >> 4, l16 = c & 15;
    for (int k = t; k < F_DIM; k += 64) {
        const float x = W[(size_t)k * ld + cl];
        const unsigned short h = f2bf(x);
        const int kh = k >> 5, qd = (k >> 3) & 3, j = k & 7;
        const size_t off = (((size_t)(ng * 16 + kh) * 64) + qd * 16 + l16) * 8 + j;
        wt_hi[off] = h;
        wt_lo[off] = f2bf(x - bf2f(h));
    }
}

// ---------------------------------------------------------------------------
// Kernel 0b: V fp32 -> bf16 hi/lo, A-frag-linear (one-shot; removes the
// per-pass VALU hi/lo split from embed's hot loop). 16 B/lane coalesced.
// ---------------------------------------------------------------------------
__global__ __launch_bounds__(256) void conv_v_kernel(
    const float* __restrict__ V,
    unsigned short* __restrict__ v_hi, unsigned short* __restrict__ v_lo)
{
    const int o   = blockIdx.x * 256 + threadIdx.x;   // octet index
    const int l16 = o & 15, kq = (o >> 4) & 3, kg = (o >> 6) & 15, rg = o >> 10;
    const int row = rg * 16 + l16;
    const int k   = kg * 32 + kq * 8;
    const float4 x0 = *(const float4*)(V + (size_t)row * F_DIM + k);
    const float4 x1 = *(const float4*)(V + (size_t)row * F_DIM + k + 4);
    const float xs[8] = {x0.x, x0.y, x0.z, x0.w, x1.x, x1.y, x1.z, x1.w};
    ushortx8 hi, lo;
    #pragma unroll
    for (int j = 0; j < 8; ++j) {
        const unsigned short h = f2bf(xs[j]);
        hi[j] = h;
        lo[j] = f2bf(xs[j] - bf2f(h));
    }
    *(ushortx8*)(v_hi + (size_t)o * 8) = hi;
    *(ushortx8*)(v_lo + (size_t)o * 8) = lo;
}

// ---------------------------------------------------------------------------
// Kernel 1: embed GEMM v3 — no LDS, no barriers, ROW-SPLIT waves (round-6
// post-mortem: col-split waves quadrupled per-CU A-traffic through L2; now
// each wave's A-frags are private). Wave w: rows wr*32..+32 (wr=w&1, 2 row
// groups), cols wcol*64..+64 (wcol=w>>1, 4 col groups). A from frag-linear
// v_hi/v_lo (bf16, pre-converted), B from frag-linear wt (1.3 MB, L2-hot).
// blockIdx.y: 0 -> f|g fused (hi/lo 3-MFMA path), 1..4 -> h cols (y-1)*128.
// Grid (256,5): x%8 -> XCD, so each XCD re-reads the same 2 MB v slice in
// all 5 passes (L2-resident).
// ---------------------------------------------------------------------------
#define BM 64

__global__ __launch_bounds__(256, 4) void embed_mfma_kernel(
    const unsigned short* __restrict__ v_hi, const unsigned short* __restrict__ v_lo,
    const unsigned short* __restrict__ wt_hi, const unsigned short* __restrict__ wt_lo,
    const float* __restrict__ bf, const float* __restrict__ bg,
    const float* __restrict__ bh,
    unsigned short* __restrict__ f_bf, unsigned short* __restrict__ g_bf,
    unsigned short* __restrict__ h_sw)
{
    const int t  = threadIdx.x;
    const int q  = blockIdx.x;            // row-tile 0..255
    const int yb = blockIdx.y;            // col-pass 0..4
    const int R0 = q * BM;
    const bool fg = (yb == 0);
    const int cbase = fg ? 0 : yb * 128;  // wt col base (g at 64, h at 128+)

    const int w = t >> 6, lane = t & 63, quad = lane >> 4, l16 = lane & 15;
    const int wr = w & 1, wcol = w >> 1;      // rows wr*32, cols wcol*64
    const int ng0 = (cbase >> 4) + wcol * 4;  // 4 col groups
    const int rg0 = q * 4 + wr * 2;           // 2 row groups

    floatx4 acc[2][4];
    #pragma unroll
    for (int rt = 0; rt < 2; ++rt)
        #pragma unroll
        for (int c = 0; c < 4; ++c)
            acc[rt][c] = (floatx4){0.f, 0.f, 0.f, 0.f};

    #pragma unroll 2
    for (int kg = 0; kg < 16; ++kg) {
        const bf16x8 a0 = *(const bf16x8*)(v_hi + (((size_t)rg0 * 16 + kg) * 64 + lane) * 8);
        const bf16x8 a1 = *(const bf16x8*)(v_hi + (((size_t)(rg0 + 1) * 16 + kg) * 64 + lane) * 8);
        bf16x8 b[4];
        #pragma unroll
        for (int c = 0; c < 4; ++c)
            b[c] = *(const bf16x8*)(wt_hi + (((size_t)(ng0 + c) * 16 + kg) * 64 + lane) * 8);
        #pragma unroll
        for (int c = 0; c < 4; ++c) {
            acc[0][c] = __builtin_amdgcn_mfma_f32_16x16x32_bf16(a0, b[c], acc[0][c], 0, 0, 0);
            acc[1][c] = __builtin_amdgcn_mfma_f32_16x16x32_bf16(a1, b[c], acc[1][c], 0, 0, 0);
        }
        if (fg) {
            const bf16x8 a0l = *(const bf16x8*)(v_lo + (((size_t)rg0 * 16 + kg) * 64 + lane) * 8);
            const bf16x8 a1l = *(const bf16x8*)(v_lo + (((size_t)(rg0 + 1) * 16 + kg) * 64 + lane) * 8);
            #pragma unroll
            for (int c = 0; c < 4; ++c) {
                const bf16x8 bl = *(const bf16x8*)(wt_lo + (((size_t)(ng0 + c) * 16 + kg) * 64 + lane) * 8);
                acc[0][c] = __builtin_amdgcn_mfma_f32_16x16x32_bf16(a0,  bl,   acc[0][c], 0, 0, 0);
                acc[0][c] = __builtin_amdgcn_mfma_f32_16x16x32_bf16(a0l, b[c], acc[0][c], 0, 0, 0);
                acc[1][c] = __builtin_amdgcn_mfma_f32_16x16x32_bf16(a1,  bl,   acc[1][c], 0, 0, 0);
                acc[1][c] = __builtin_amdgcn_mfma_f32_16x16x32_bf16(a1l, b[c], acc[1][c], 0, 0, 0);
            }
        }
    }

    // ---- epilogue: bias + relu + bf16, route by wt column ----
    #pragma unroll
    for (int rt = 0; rt < 2; ++rt) {
        #pragma unroll
        for (int c = 0; c < 4; ++c) {
            const int wtc  = cbase + wcol * 64 + c * 16 + l16;   // 0..639
            const int rowl = wr * 32 + rt * 16 + quad * 4;
            const float bias = fg ? (wtc < 64 ? bf[wtc] : bg[wtc - 64]) : bh[wtc - 128];
            const floatx4 v = acc[rt][c];
            if (fg) {
                unsigned short* dst = (wtc < 64) ? (f_bf + wtc) : (g_bf + wtc - 64);
                #pragma unroll
                for (int r = 0; r < 4; ++r) {
                    const float z = v[r] + bias;
                    dst[(size_t)(R0 + rowl + r) * C_DIM] = f2bf(z > 0.f ? z : 0.f);
                }
            } else {
                const int hc   = wtc - 128;                   // global F col
                const int grow = R0 + rowl;
                const int b    = grow >> 12, rl = grow & 4095;
                const int T    = rl >> 6, mloc = rl & 63;
                const int kh2  = mloc >> 5, q2 = (mloc >> 3) & 3, j0 = mloc & 7;
                ushortx4 st;
                #pragma unroll
                for (int r = 0; r < 4; ++r) {
                    const float z = v[r] + bias;
                    st[r] = f2bf(z > 0.f ? z : 0.f);
                }
                const size_t off = ((((size_t)(b * 64 + T) * 64) + (hc >> 4) * 2 + kh2) * 64
                                    + q2 * 16 + (hc & 15)) * 8 + j0;
                *(ushortx4*)(h_sw + off) = st;
            }
        }
    }
}

// ---------------------------------------------------------------------------
// Kernel 2: MFMA attention = R1's verified kernel (92 us, 0 conflicts) +
// DUAL-HALF KT=128: two 64-key subtiles per barrier pair as SEPARATE
// stride-128 LDS buffers (round-6 post-mortem: a single stride-256 tile
// broke the swizzle -> 1.7e7 conflicts; stride-128 + (row&7)<<4 is the
// verified-0 pattern). 32 iters x 36 MFMA/wave per pair (R0's density).
//
// QT=64, 1024 threads (16 waves), grid = 4b x 64 qt = 256 blocks, fused
// softmax + epilogue (full 4096 keys per block). Scores: wave w -> rows
// (w&3)*16, cols (w>>2)*16 of each half's 64x64 tile. PV: wave w -> all 64
// rows x 32 F-cols (w*32); h groups 4w..4w+3 of each of the 2 mtiles.
// Barriers lgkm-only. XCD map: chunked (bid&7)*32+(bid>>3) -> each XCD
// streams one batch's 2 MB h, L2-resident.
// ---------------------------------------------------------------------------
#define QT 64

__global__ __launch_bounds__(1024, 4) void attn_mfma_kernel(
    const unsigned short* __restrict__ f_bf, const unsigned short* __restrict__ g_bf,
    const unsigned short* __restrict__ h_sw, const float* __restrict__ gamma,
    const float* __restrict__ V, float* __restrict__ out)
{
    __shared__ __align__(16) unsigned short p_lds[2][2][QT * 64];   // 32 KB
    __shared__ __align__(16) unsigned short g_lds[2][2][64 * 64];   // 32 KB
    __shared__ float l_red[4][QT];
    __shared__ float l_inv[QT];

    const int t = threadIdx.x;
    const int w = t >> 6, lane = t & 63, quad = lane >> 4, l16 = lane & 15;
    const int wr = w & 3, wc = w >> 2;     // score stripe: rows wr*16, cols wc*16

    // XCD-chunked: XCD x (=bid&7) gets 32 consecutive q-tiles of one batch.
    const int bid  = blockIdx.x;
    const int orig = (bid & 7) * 32 + (bid >> 3);
    const int b    = orig >> 6, qb = orig & 63;
    const int R0   = qb * QT;

    const unsigned short* fb    = f_bf + ((size_t)b * 4096 + R0) * C_DIM;
    const unsigned short* gb    = g_bf + (size_t)b * 4096 * C_DIM;
    const unsigned short* hbase = h_sw + (size_t)b * 64 * 32768;

    bf16x8 f0, f1;
    {
        const unsigned short* fr = fb + (size_t)(wr * 16 + l16) * C_DIM + quad * 8;
        f0 = *(const bf16x8*)fr;
        f1 = *(const bf16x8*)(fr + 32);
    }
    const float gam0 = gamma[w * 32 + l16];
    const float gam1 = gamma[w * 32 + 16 + l16];

    floatx4 acc[4][2];   // [row-tile][col-16-group]; cols w*32 + c*16
    #pragma unroll
    for (int rt = 0; rt < 4; ++rt)
        #pragma unroll
        for (int c = 0; c < 2; ++c)
            acc[rt][c] = (floatx4){0.f, 0.f, 0.f, 0.f};
    float run_l[4] = {0.f, 0.f, 0.f, 0.f};

    // cooperative g stage: 1024 threads x 16 B = 16 KB (2 halves of 8 KB).
    // thread t -> grow = t>>3 (0..127): half = grow>>6, row r64 = grow&63.
    const int grow = t >> 3, gchunk = t & 7;
    const int ghalf = grow >> 6, gr64 = grow & 63;
    const int g_swoff = gr64 * 128 + ((gchunk * 16) ^ ((gr64 & 7) << 4));
    ushortx8 greg = *(const ushortx8*)(gb + (size_t)grow * C_DIM + gchunk * 8);

    // loop-invariant swizzled score-read offsets (R1's verified pattern)
    const int sgrow   = wc * 16 + l16;
    const int sg_off0 = sgrow * 128 + ((quad * 16)      ^ ((sgrow & 7) << 4));
    const int sg_off1 = sgrow * 128 + ((quad * 16 + 64) ^ ((sgrow & 7) << 4));

    for (int it = 0; it < 32; ++it) {
        const int buf = it & 1;

        // ---- h prefetch: groups 4w..4w+3 of both 64-key mtiles (8 KB) ----
        const unsigned short* ht0 = hbase + (size_t)(2 * it) * 32768 + (size_t)(4 * w) * 512;
        const unsigned short* ht1 = ht0 + 32768;
        bf16x8 h[2][4];
        #pragma unroll
        for (int gi = 0; gi < 4; ++gi) {
            h[0][gi] = *(const bf16x8*)(ht0 + gi * 512 + (size_t)lane * 8);
            h[1][gi] = *(const bf16x8*)(ht1 + gi * 512 + (size_t)lane * 8);
        }

        *(ushortx8*)((unsigned char*)&g_lds[buf][ghalf][0] + g_swoff) = greg;
        if (it < 31)
            greg = *(const ushortx8*)(gb + (size_t)((it + 1) * 128 + grow) * C_DIM + gchunk * 8);
        lgkm_barrier();   // g[buf] visible

        // ---- scores: per half s, rows wr*16..+16 x cols wc*16..+16 ----
        #pragma unroll
        for (int s = 0; s < 2; ++s) {
            const unsigned char* gB = (const unsigned char*)&g_lds[buf][s][0];
            unsigned char*       pB = (unsigned char*)&p_lds[buf][s][0];
            const bf16x8 g0 = *(const bf16x8*)(gB + sg_off0);
            const bf16x8 g1 = *(const bf16x8*)(gB + sg_off1);
            floatx4 cc = (floatx4){0.f, 0.f, 0.f, 0.f};
            cc = __builtin_amdgcn_mfma_f32_16x16x32_bf16(f0, g0, cc, 0, 0, 0);
            cc = __builtin_amdgcn_mfma_f32_16x16x32_bf16(f1, g1, cc, 0, 0, 0);
            #pragma unroll
            for (int r = 0; r < 4; ++r) {
                const float p = __expf(cc[r] - 32.f);
                run_l[r] += p;
                const int prow = wr * 16 + quad * 4 + r;
                const int pcol = wc * 16 + l16;
                *(unsigned short*)(pB + prow * 128 + ((pcol * 2) ^ ((prow & 7) << 4))) = f2bf(p);
            }
        }
        lgkm_barrier();   // p[buf] visible

        // ---- PV: all 64 rows x wave's 32 cols, both halves ----
        #pragma unroll
        for (int rt = 0; rt < 4; ++rt) {
            const int prow = rt * 16 + l16;
            const int sw   = (prow & 7) << 4;
            #pragma unroll
            for (int s = 0; s < 2; ++s) {
                const unsigned char* pB = (const unsigned char*)&p_lds[buf][s][0];
                const bf16x8 pf0 = *(const bf16x8*)(pB + prow * 128 + ((quad * 16)      ^ sw));
                const bf16x8 pf1 = *(const bf16x8*)(pB + prow * 128 + ((quad * 16 + 64) ^ sw));
                acc[rt][0] = __builtin_amdgcn_mfma_f32_16x16x32_bf16(pf0, h[s][0], acc[rt][0], 0, 0, 0);
                acc[rt][0] = __builtin_amdgcn_mfma_f32_16x16x32_bf16(pf1, h[s][1], acc[rt][0], 0, 0, 0);
                acc[rt][1] = __builtin_amdgcn_mfma_f32_16x16x32_bf16(pf0, h[s][2], acc[rt][1], 0, 0, 0);
                acc[rt][1] = __builtin_amdgcn_mfma_f32_16x16x32_bf16(pf1, h[s][3], acc[rt][1], 0, 0, 0);
            }
        }
    }

    // ---- full row-sum l: shfl over l16, then LDS-sum across the 4 wc ----
    #pragma unroll
    for (int r = 0; r < 4; ++r) {
        float v = run_l[r];
        v += __shfl_xor(v, 1, 64);
        v += __shfl_xor(v, 2, 64);
        v += __shfl_xor(v, 4, 64);
        v += __shfl_xor(v, 8, 64);
        if (l16 == 0) l_red[wc][wr * 16 + quad * 4 + r] = v;
    }
    __syncthreads();
    if (t < QT)
        l_inv[t] = 1.f / (l_red[0][t] + l_red[1][t] + l_red[2][t] + l_red[3][t]);
    __syncthreads();

    // ---- fused epilogue: out = gamma * O/l + V (fp32, final) ----
    const float* Vb = V   + ((size_t)b * 4096 + R0) * F_DIM;
    float*       ob = out + ((size_t)b * 4096 + R0) * F_DIM;
    #pragma unroll
    for (int rt = 0; rt < 4; ++rt) {
        #pragma unroll
        for (int r = 0; r < 4; ++r) {
            const int row = rt * 16 + quad * 4 + r;
            const float li = l_inv[row];
            const int c0 = w * 32 + l16;
            ob[(size_t)row * F_DIM + c0]      = gam0 * acc[rt][0][r] * li + Vb[(size_t)row * F_DIM + c0];
            ob[(size_t)row * F_DIM + c0 + 16] = gam1 * acc[rt][1][r] * li + Vb[(size_t)row * F_DIM + c0 + 16];
        }
    }
}

// ---------------------------------------------------------------------------
extern "C" void kernel_launch(void* const* d_in, const int* in_sizes, int n_in,
                              void* d_out, int out_size, void* d_ws, size_t ws_size,
                              hipStream_t stream) {
    const float* V     = (const float*)d_in[0];
    const float* Wf    = (const float*)d_in[1];
    const float* bf    = (const float*)d_in[2];
    const float* Wg    = (const float*)d_in[3];
    const float* bg    = (const float*)d_in[4];
    const float* Wh    = (const float*)d_in[5];
    const float* bh    = (const float*)d_in[6];
    const float* gamma = (const float*)d_in[7];
    float* out = (float*)d_out;

    // ws: f 2MB | g 2MB | h_sw 16MB | wt_hi 0.64 | wt_lo 0.64 | v_hi 16MB | v_lo 16MB
    unsigned short* f_bf  = (unsigned short*)d_ws;
    unsigned short* g_bf  = f_bf + (size_t)M_ROWS * C_DIM;
    unsigned short* h_sw  = g_bf + (size_t)M_ROWS * C_DIM;
    unsigned short* wt_hi = h_sw + (size_t)4 * F_DIM * 4096;
    unsigned short* wt_lo = wt_hi + (size_t)640 * F_DIM;
    unsigned short* v_hi  = wt_lo + (size_t)640 * F_DIM;
    unsigned short* v_lo  = v_hi + (size_t)M_ROWS * F_DIM;

    conv_v_kernel<<<M_ROWS * F_DIM / 8 / 256, 256, 0, stream>>>(V, v_hi, v_lo);
    prep_w_kernel<<<640, 64, 0, stream>>>(Wf, Wg, Wh, wt_hi, wt_lo);
    embed_mfma_kernel<<<dim3(256, 5), 256, 0, stream>>>(
        v_hi, v_lo, wt_hi, wt_lo, bf, bg, bh, f_bf, g_bf, h_sw);
    attn_mfma_kernel<<<256, 1024, 0, stream>>>(f_bf, g_bf, h_sw, gamma, V, out);
}

// Round 8
// 204.400 us; speedup vs baseline: 1.2082x; 1.0672x over previous
//
#include <hip/hip_runtime.h>
#include <hip/hip_bf16.h>
#include <math.h>

// B=4, N=4096, F=512, C=64. M = B*N = 16384 rows.
#define M_ROWS 16384
#define F_DIM 512
#define C_DIM 64

typedef short bf16x8 __attribute__((ext_vector_type(8)));
typedef float floatx4 __attribute__((ext_vector_type(4)));
typedef unsigned short ushortx8 __attribute__((ext_vector_type(8)));
typedef unsigned short ushortx4 __attribute__((ext_vector_type(4)));

static __device__ __forceinline__ unsigned short f2bf(float x) {
    __hip_bfloat16 h = __float2bfloat16(x);   // RN
    return *reinterpret_cast<unsigned short*>(&h);
}
static __device__ __forceinline__ float bf2f(unsigned short h) {
    unsigned int u = ((unsigned int)h) << 16;
    return __builtin_bit_cast(float, u);
}

// LDS-only barrier: global loads stay in flight (no vmcnt(0) drain).
static __device__ __forceinline__ void lgkm_barrier() {
    asm volatile("s_waitcnt lgkmcnt(0)\n\ts_barrier" ::: "memory");
}

// ---------------------------------------------------------------------------
// Frag-linear layouts (MFMA B-operand order): element (n,k) of a 16-col group
// lives at lane=(k>>3&3)*16+(n&15), j=k&7 -> [group][lane][8] contiguous.
//   wt    : group = (c>>4)*16 + (k>>5)            (640 cols x 512 k)
//   h_sw  : [b][mtile(64)][group=(Fcol>>4)*2+(mloc>>5)][lane][8]
// ---------------------------------------------------------------------------

// Kernel 0: weight transpose + bf16 hi/lo split -> frag-linear.
__global__ __launch_bounds__(64) void prep_w_kernel(
    const float* __restrict__ Wf, const float* __restrict__ Wg,
    const float* __restrict__ Wh,
    unsigned short* __restrict__ wt_hi, unsigned short* __restrict__ wt_lo)
{
    const int c = blockIdx.x;
    const int t = threadIdx.x;
    const float* W; int ld, cl;
    if (c < 64)       { W = Wf; ld = C_DIM; cl = c; }
    else if (c < 128) { W = Wg; ld = C_DIM; cl = c - 64; }
    else              { W = Wh; ld = F_DIM; cl = c - 128; }
    const int ng = c >> 4, l16 = c & 15;
    for (int k = t; k < F_DIM; k += 64) {
        const float x = W[(size_t)k * ld + cl];
        const unsigned short h = f2bf(x);
        const int kh = k >> 5, qd = (k >> 3) & 3, j = k & 7;
        const size_t off = (((size_t)(ng * 16 + kh) * 64) + qd * 16 + l16) * 8 + j;
        wt_hi[off] = h;
        wt_lo[off] = f2bf(x - bf2f(h));
    }
}

// ---------------------------------------------------------------------------
// Kernel 1: MFMA embed GEMM — REVERTED to the verified R0-R4 LDS version
// (round-7 post-mortem: the no-LDS frag-linear path regressed rest-time
// 108 -> 124 us; this version is the measured-best embed). 64 rows x 128
// cols per block. blockIdx.y: 0 -> f|g fused (hi/lo 3-MFMA path), 1..4 ->
// h cols (y-1)*128. Wave w owns cols w*32..+32.
// ---------------------------------------------------------------------------
#define BM 64
#define LDK 72

__global__ __launch_bounds__(256, 4) void embed_mfma_kernel(
    const float* __restrict__ V,
    const unsigned short* __restrict__ wt_hi, const unsigned short* __restrict__ wt_lo,
    const float* __restrict__ bf, const float* __restrict__ bg,
    const float* __restrict__ bh,
    unsigned short* __restrict__ f_bf, unsigned short* __restrict__ g_bf,
    unsigned short* __restrict__ h_sw)
{
    __shared__ __align__(16) unsigned short a_hi[BM][LDK];
    __shared__ __align__(16) unsigned short a_lo[BM][LDK];

    const int t  = threadIdx.x;
    const int R0 = blockIdx.x * BM;
    const bool fg = (blockIdx.y == 0);
    const int cbase = fg ? 0 : blockIdx.y * 128;   // wt col base (g at 64, h at 128+)

    const int w = t >> 6, lane = t & 63, quad = lane >> 4, l16 = lane & 15;

    floatx4 acc[4][2];
    #pragma unroll
    for (int rt = 0; rt < 4; ++rt)
        #pragma unroll
        for (int c = 0; c < 2; ++c)
            acc[rt][c] = (floatx4){0.f, 0.f, 0.f, 0.f};

    const int arow = t >> 4;          // 0..15 (+16/round)
    const int acol = (t & 15) * 4;    // float index (16 B chunks)
    const int ng0  = (cbase >> 4) + w * 2;

    #pragma unroll 1
    for (int k0 = 0; k0 < F_DIM; k0 += 64) {
        lgkm_barrier();   // protect previous iteration's a-frag reads
        // ---- stage A: V fp32 -> bf16 hi/lo in LDS ----
        #pragma unroll
        for (int rr = 0; rr < 4; ++rr) {
            const int row = rr * 16 + arow;
            const float4 x = *(const float4*)(V + (size_t)(R0 + row) * F_DIM + k0 + acol);
            const float xs[4] = {x.x, x.y, x.z, x.w};
            ushortx4 hi, lo;
            #pragma unroll
            for (int jj = 0; jj < 4; ++jj) {
                const unsigned short hb2 = f2bf(xs[jj]);
                hi[jj] = hb2;
                lo[jj] = f2bf(xs[jj] - bf2f(hb2));
            }
            *(ushortx4*)&a_hi[row][acol] = hi;
            if (fg) *(ushortx4*)&a_lo[row][acol] = lo;
        }
        lgkm_barrier();
        // ---- compute ----
        #pragma unroll
        for (int kk = 0; kk < 2; ++kk) {
            const int kh = (k0 >> 5) + kk;
            const bf16x8 b0 = *(const bf16x8*)(wt_hi + (((size_t)(ng0 * 16 + kh)) * 64 + lane) * 8);
            const bf16x8 b1 = *(const bf16x8*)(wt_hi + (((size_t)((ng0 + 1) * 16 + kh)) * 64 + lane) * 8);
            bf16x8 ah[4];
            #pragma unroll
            for (int rt = 0; rt < 4; ++rt)
                ah[rt] = *(const bf16x8*)&a_hi[rt * 16 + l16][kk * 32 + quad * 8];
            #pragma unroll
            for (int rt = 0; rt < 4; ++rt) {
                acc[rt][0] = __builtin_amdgcn_mfma_f32_16x16x32_bf16(ah[rt], b0, acc[rt][0], 0, 0, 0);
                acc[rt][1] = __builtin_amdgcn_mfma_f32_16x16x32_bf16(ah[rt], b1, acc[rt][1], 0, 0, 0);
            }
            if (fg) {
                const bf16x8 c0 = *(const bf16x8*)(wt_lo + (((size_t)(ng0 * 16 + kh)) * 64 + lane) * 8);
                const bf16x8 c1 = *(const bf16x8*)(wt_lo + (((size_t)((ng0 + 1) * 16 + kh)) * 64 + lane) * 8);
                bf16x8 al[4];
                #pragma unroll
                for (int rt = 0; rt < 4; ++rt)
                    al[rt] = *(const bf16x8*)&a_lo[rt * 16 + l16][kk * 32 + quad * 8];
                #pragma unroll
                for (int rt = 0; rt < 4; ++rt) {
                    acc[rt][0] = __builtin_amdgcn_mfma_f32_16x16x32_bf16(ah[rt], c0, acc[rt][0], 0, 0, 0);
                    acc[rt][0] = __builtin_amdgcn_mfma_f32_16x16x32_bf16(al[rt], b0, acc[rt][0], 0, 0, 0);
                    acc[rt][1] = __builtin_amdgcn_mfma_f32_16x16x32_bf16(ah[rt], c1, acc[rt][1], 0, 0, 0);
                    acc[rt][1] = __builtin_amdgcn_mfma_f32_16x16x32_bf16(al[rt], b1, acc[rt][1], 0, 0, 0);
                }
            }
        }
    }

    // ---- epilogue: bias + relu + bf16, route by wt column ----
    #pragma unroll
    for (int rt = 0; rt < 4; ++rt) {
        #pragma unroll
        for (int c = 0; c < 2; ++c) {
            const int wtc  = cbase + w * 32 + c * 16 + l16;   // 0..639
            const int rowl = rt * 16 + quad * 4;
            const float bias = fg ? (wtc < 64 ? bf[wtc] : bg[wtc - 64]) : bh[wtc - 128];
            const floatx4 v = acc[rt][c];
            if (fg) {
                unsigned short* dst = (wtc < 64) ? (f_bf + wtc) : (g_bf + wtc - 64);
                #pragma unroll
                for (int r = 0; r < 4; ++r) {
                    const float z = v[r] + bias;
                    dst[(size_t)(R0 + rowl + r) * C_DIM] = f2bf(z > 0.f ? z : 0.f);
                }
            } else {
                const int hc   = wtc - 128;                   // global F col
                const int grow = R0 + rowl;
                const int b    = grow >> 12, rl = grow & 4095;
                const int T    = rl >> 6, mloc = rl & 63;
                const int kh2  = mloc >> 5, q2 = (mloc >> 3) & 3, j0 = mloc & 7;
                ushortx4 st;
                #pragma unroll
                for (int r = 0; r < 4; ++r) {
                    const float z = v[r] + bias;
                    st[r] = f2bf(z > 0.f ? z : 0.f);
                }
                const size_t off = ((((size_t)(b * 64 + T) * 64) + (hc >> 4) * 2 + kh2) * 64
                                    + q2 * 16 + (hc & 15)) * 8 + j0;
                *(ushortx4*)(h_sw + off) = st;
            }
        }
    }
}

// ---------------------------------------------------------------------------
// Kernel 2: MFMA attention — R7's verified dual-half layout (0 conflicts) +
// 1-ITERATION SKEW PIPELINE (round-7 post-mortem: halving barriers did
// nothing; the cost is the 2-phase scores->barrier->PV lockstep). Now each
// iter does {h-load(it-1), stage g(it), ONE barrier, scores(it)->p[it&1],
// PV(it-1) from p[(it-1)&1]} — scores' exp/VALU overlaps PV's MFMA, and
// barriers drop 64 -> 33. T5 setprio around the PV MFMA cluster (role
// diversity now exists). Hazards: every p/g buffer reuse is separated by
// an intervening lgkmcnt(0)+barrier (audited).
//
// QT=64, 1024 threads (16 waves), grid = 4b x 64 qt = 256 blocks, fused
// softmax + epilogue. Scores: wave w -> rows (w&3)*16, cols (w>>2)*16 of
// each half's 64x64 tile. PV: wave w -> all 64 rows x 32 F-cols (w*32).
// LDS stride-128 + (row&7)<<4 XOR-swizzle throughout (verified-0 pattern).
// XCD map: chunked (bid&7)*32+(bid>>3).
// ---------------------------------------------------------------------------
#define QT 64

__global__ __launch_bounds__(1024, 4) void attn_mfma_kernel(
    const unsigned short* __restrict__ f_bf, const unsigned short* __restrict__ g_bf,
    const unsigned short* __restrict__ h_sw, const float* __restrict__ gamma,
    const float* __restrict__ V, float* __restrict__ out)
{
    __shared__ __align__(16) unsigned short p_lds[2][2][QT * 64];   // 32 KB
    __shared__ __align__(16) unsigned short g_lds[2][2][64 * 64];   // 32 KB
    __shared__ float l_red[4][QT];
    __shared__ float l_inv[QT];

    const int t = threadIdx.x;
    const int w = t >> 6, lane = t & 63, quad = lane >> 4, l16 = lane & 15;
    const int wr = w & 3, wc = w >> 2;     // score stripe: rows wr*16, cols wc*16

    // XCD-chunked: XCD x (=bid&7) gets 32 consecutive q-tiles of one batch.
    const int bid  = blockIdx.x;
    const int orig = (bid & 7) * 32 + (bid >> 3);
    const int b    = orig >> 6, qb = orig & 63;
    const int R0   = qb * QT;

    const unsigned short* fb    = f_bf + ((size_t)b * 4096 + R0) * C_DIM;
    const unsigned short* gb    = g_bf + (size_t)b * 4096 * C_DIM;
    const unsigned short* hbase = h_sw + (size_t)b * 64 * 32768;

    bf16x8 f0, f1;
    {
        const unsigned short* fr = fb + (size_t)(wr * 16 + l16) * C_DIM + quad * 8;
        f0 = *(const bf16x8*)fr;
        f1 = *(const bf16x8*)(fr + 32);
    }
    const float gam0 = gamma[w * 32 + l16];
    const float gam1 = gamma[w * 32 + 16 + l16];

    floatx4 acc[4][2];   // [row-tile][col-16-group]; cols w*32 + c*16
    #pragma unroll
    for (int rt = 0; rt < 4; ++rt)
        #pragma unroll
        for (int c = 0; c < 2; ++c)
            acc[rt][c] = (floatx4){0.f, 0.f, 0.f, 0.f};
    float run_l[4] = {0.f, 0.f, 0.f, 0.f};

    // cooperative g stage: 1024 threads x 16 B = 16 KB (2 halves of 8 KB).
    const int grow = t >> 3, gchunk = t & 7;
    const int ghalf = grow >> 6, gr64 = grow & 63;
    const int g_swoff = gr64 * 128 + ((gchunk * 16) ^ ((gr64 & 7) << 4));
    ushortx8 greg = *(const ushortx8*)(gb + (size_t)grow * C_DIM + gchunk * 8);

    // loop-invariant swizzled score-read offsets (verified pattern)
    const int sgrow   = wc * 16 + l16;
    const int sg_off0 = sgrow * 128 + ((quad * 16)      ^ ((sgrow & 7) << 4));
    const int sg_off1 = sgrow * 128 + ((quad * 16 + 64) ^ ((sgrow & 7) << 4));

    // ---- peel it=0: stage g(0), scores(0) -> p[0] ----
    *(ushortx8*)((unsigned char*)&g_lds[0][ghalf][0] + g_swoff) = greg;
    greg = *(const ushortx8*)(gb + (size_t)(128 + grow) * C_DIM + gchunk * 8);
    lgkm_barrier();
    #pragma unroll
    for (int s = 0; s < 2; ++s) {
        const unsigned char* gB = (const unsigned char*)&g_lds[0][s][0];
        unsigned char*       pB = (unsigned char*)&p_lds[0][s][0];
        const bf16x8 g0 = *(const bf16x8*)(gB + sg_off0);
        const bf16x8 g1 = *(const bf16x8*)(gB + sg_off1);
        floatx4 cc = (floatx4){0.f, 0.f, 0.f, 0.f};
        cc = __builtin_amdgcn_mfma_f32_16x16x32_bf16(f0, g0, cc, 0, 0, 0);
        cc = __builtin_amdgcn_mfma_f32_16x16x32_bf16(f1, g1, cc, 0, 0, 0);
        #pragma unroll
        for (int r = 0; r < 4; ++r) {
            const float p = __expf(cc[r] - 32.f);
            run_l[r] += p;
            const int prow = wr * 16 + quad * 4 + r;
            const int pcol = wc * 16 + l16;
            *(unsigned short*)(pB + prow * 128 + ((pcol * 2) ^ ((prow & 7) << 4))) = f2bf(p);
        }
    }

    bf16x8 h[2][4];

    // ---- main loop: scores(it) || PV(it-1) ----
    for (int it = 1; it < 32; ++it) {
        const int buf = it & 1, pb = buf ^ 1;

        // h for key-tile it-1 (consumed by PV this iter; latency hidden
        // under stage + barrier + scores)
        const unsigned short* ht0 = hbase + (size_t)(2 * (it - 1)) * 32768 + (size_t)(4 * w) * 512;
        const unsigned short* ht1 = ht0 + 32768;
        #pragma unroll
        for (int gi = 0; gi < 4; ++gi) {
            h[0][gi] = *(const bf16x8*)(ht0 + gi * 512 + (size_t)lane * 8);
            h[1][gi] = *(const bf16x8*)(ht1 + gi * 512 + (size_t)lane * 8);
        }

        *(ushortx8*)((unsigned char*)&g_lds[buf][ghalf][0] + g_swoff) = greg;
        if (it < 31)
            greg = *(const ushortx8*)(gb + (size_t)((it + 1) * 128 + grow) * C_DIM + gchunk * 8);
        lgkm_barrier();   // g[buf] + p[pb] (written last iter) visible

        // ---- scores(it): per half s, rows wr*16..+16 x cols wc*16..+16 ----
        #pragma unroll
        for (int s = 0; s < 2; ++s) {
            const unsigned char* gB = (const unsigned char*)&g_lds[buf][s][0];
            unsigned char*       pB = (unsigned char*)&p_lds[buf][s][0];
            const bf16x8 g0 = *(const bf16x8*)(gB + sg_off0);
            const bf16x8 g1 = *(const bf16x8*)(gB + sg_off1);
            floatx4 cc = (floatx4){0.f, 0.f, 0.f, 0.f};
            cc = __builtin_amdgcn_mfma_f32_16x16x32_bf16(f0, g0, cc, 0, 0, 0);
            cc = __builtin_amdgcn_mfma_f32_16x16x32_bf16(f1, g1, cc, 0, 0, 0);
            #pragma unroll
            for (int r = 0; r < 4; ++r) {
                const float p = __expf(cc[r] - 32.f);
                run_l[r] += p;
                const int prow = wr * 16 + quad * 4 + r;
                const int pcol = wc * 16 + l16;
                *(unsigned short*)(pB + prow * 128 + ((pcol * 2) ^ ((prow & 7) << 4))) = f2bf(p);
            }
        }

        // ---- PV(it-1): all 64 rows x wave's 32 cols, both halves ----
        __builtin_amdgcn_s_setprio(1);
        #pragma unroll
        for (int rt = 0; rt < 4; ++rt) {
            const int prow = rt * 16 + l16;
            const int sw   = (prow & 7) << 4;
            #pragma unroll
            for (int s = 0; s < 2; ++s) {
                const unsigned char* pB = (const unsigned char*)&p_lds[pb][s][0];
                const bf16x8 pf0 = *(const bf16x8*)(pB + prow * 128 + ((quad * 16)      ^ sw));
                const bf16x8 pf1 = *(const bf16x8*)(pB + prow * 128 + ((quad * 16 + 64) ^ sw));
                acc[rt][0] = __builtin_amdgcn_mfma_f32_16x16x32_bf16(pf0, h[s][0], acc[rt][0], 0, 0, 0);
                acc[rt][0] = __builtin_amdgcn_mfma_f32_16x16x32_bf16(pf1, h[s][1], acc[rt][0], 0, 0, 0);
                acc[rt][1] = __builtin_amdgcn_mfma_f32_16x16x32_bf16(pf0, h[s][2], acc[rt][1], 0, 0, 0);
                acc[rt][1] = __builtin_amdgcn_mfma_f32_16x16x32_bf16(pf1, h[s][3], acc[rt][1], 0, 0, 0);
            }
        }
        __builtin_amdgcn_s_setprio(0);
    }

    // ---- tail: PV(31) from p[1] ----
    {
        const unsigned short* ht0 = hbase + (size_t)62 * 32768 + (size_t)(4 * w) * 512;
        const unsigned short* ht1 = ht0 + 32768;
        #pragma unroll
        for (int gi = 0; gi < 4; ++gi) {
            h[0][gi] = *(const bf16x8*)(ht0 + gi * 512 + (size_t)lane * 8);
            h[1][gi] = *(const bf16x8*)(ht1 + gi * 512 + (size_t)lane * 8);
        }
        lgkm_barrier();   // p[1] writes from scores(31) visible
        #pragma unroll
        for (int rt = 0; rt < 4; ++rt) {
            const int prow = rt * 16 + l16;
            const int sw   = (prow & 7) << 4;
            #pragma unroll
            for (int s = 0; s < 2; ++s) {
                const unsigned char* pB = (const unsigned char*)&p_lds[1][s][0];
                const bf16x8 pf0 = *(const bf16x8*)(pB + prow * 128 + ((quad * 16)      ^ sw));
                const bf16x8 pf1 = *(const bf16x8*)(pB + prow * 128 + ((quad * 16 + 64) ^ sw));
                acc[rt][0] = __builtin_amdgcn_mfma_f32_16x16x32_bf16(pf0, h[s][0], acc[rt][0], 0, 0, 0);
                acc[rt][0] = __builtin_amdgcn_mfma_f32_16x16x32_bf16(pf1, h[s][1], acc[rt][0], 0, 0, 0);
                acc[rt][1] = __builtin_amdgcn_mfma_f32_16x16x32_bf16(pf0, h[s][2], acc[rt][1], 0, 0, 0);
                acc[rt][1] = __builtin_amdgcn_mfma_f32_16x16x32_bf16(pf1, h[s][3], acc[rt][1], 0, 0, 0);
            }
        }
    }

    // ---- full row-sum l: shfl over l16, then LDS-sum across the 4 wc ----
    #pragma unroll
    for (int r = 0; r < 4; ++r) {
        float v = run_l[r];
        v += __shfl_xor(v, 1, 64);
        v += __shfl_xor(v, 2, 64);
        v += __shfl_xor(v, 4, 64);
        v += __shfl_xor(v, 8, 64);
        if (l16 == 0) l_red[wc][wr * 16 + quad * 4 + r] = v;
    }
    __syncthreads();
    if (t < QT)
        l_inv[t] = 1.f / (l_red[0][t] + l_red[1][t] + l_red[2][t] + l_red[3][t]);
    __syncthreads();

    // ---- fused epilogue: out = gamma * O/l + V (fp32, final) ----
    const float* Vb = V   + ((size_t)b * 4096 + R0) * F_DIM;
    float*       ob = out + ((size_t)b * 4096 + R0) * F_DIM;
    #pragma unroll
    for (int rt = 0; rt < 4; ++rt) {
        #pragma unroll
        for (int r = 0; r < 4; ++r) {
            const int row = rt * 16 + quad * 4 + r;
            const float li = l_inv[row];
            const int c0 = w * 32 + l16;
            ob[(size_t)row * F_DIM + c0]      = gam0 * acc[rt][0][r] * li + Vb[(size_t)row * F_DIM + c0];
            ob[(size_t)row * F_DIM + c0 + 16] = gam1 * acc[rt][1][r] * li + Vb[(size_t)row * F_DIM + c0 + 16];
        }
    }
}

// ---------------------------------------------------------------------------
extern "C" void kernel_launch(void* const* d_in, const int* in_sizes, int n_in,
                              void* d_out, int out_size, void* d_ws, size_t ws_size,
                              hipStream_t stream) {
    const float* V     = (const float*)d_in[0];
    const float* Wf    = (const float*)d_in[1];
    const float* bf    = (const float*)d_in[2];
    const float* Wg    = (const float*)d_in[3];
    const float* bg    = (const float*)d_in[4];
    const float* Wh    = (const float*)d_in[5];
    const float* bh    = (const float*)d_in[6];
    const float* gamma = (const float*)d_in[7];
    float* out = (float*)d_out;

    // ws: f 2MB | g 2MB | h_sw 16MB | wt_hi 0.64 | wt_lo 0.64
    unsigned short* f_bf  = (unsigned short*)d_ws;
    unsigned short* g_bf  = f_bf + (size_t)M_ROWS * C_DIM;
    unsigned short* h_sw  = g_bf + (size_t)M_ROWS * C_DIM;
    unsigned short* wt_hi = h_sw + (size_t)4 * F_DIM * 4096;
    unsigned short* wt_lo = wt_hi + (size_t)640 * F_DIM;

    prep_w_kernel<<<640, 64, 0, stream>>>(Wf, Wg, Wh, wt_hi, wt_lo);
    embed_mfma_kernel<<<dim3(M_ROWS / BM, 5), 256, 0, stream>>>(
        V, wt_hi, wt_lo, bf, bg, bh, f_bf, g_bf, h_sw);
    attn_mfma_kernel<<<256, 1024, 0, stream>>>(f_bf, g_bf, h_sw, gamma, V, out);
}